// Round 19
// baseline (174.134 us; speedup 1.0000x reference)
//
#include <hip/hip_runtime.h>
#include <hip/hip_bf16.h>
#include <stdint.h>

typedef __bf16 bf16x8 __attribute__((ext_vector_type(8)));
typedef float  f32x4  __attribute__((ext_vector_type(4)));

#define B_   4
#define S_   2048
#define DM   1024
#define H_   16
#define DK   64
#define M_TOT 8192

// ---------------------------------------------------------------------------
__device__ __forceinline__ void gld16(const __bf16* g, char* l) {
    __builtin_amdgcn_global_load_lds(
        (const __attribute__((address_space(1))) void*)g,
        (__attribute__((address_space(3))) void*)l,
        16, 0, 0);
}

// ---------------------------------------------------------------------------
// One dispatch: x (8.4M elems) then 4 weight matrices (4x1M) -> bf16.
// Block-uniform path select (2048 elems/block; x ends exactly at block 4096).
__global__ __launch_bounds__(256)
void cvt_all(const float* __restrict__ x,
             const float* __restrict__ w0, const float* __restrict__ w1,
             const float* __restrict__ w2, const float* __restrict__ w3,
             __bf16* __restrict__ xb, __bf16* __restrict__ wb) {
    int i = (blockIdx.x * 256 + threadIdx.x) * 8;
    const float* in;
    __bf16* out;
    if (i < M_TOT * DM) {
        in = x + i; out = xb + i;
    } else {
        int j = i - M_TOT * DM;          // 0 .. 4*1048576-1
        int w = j >> 20;
        const float* ws4[4] = {w0, w1, w2, w3};
        in = ws4[w] + (j & 1048575); out = wb + j;
    }
    float4 a = *(const float4*)in;
    float4 c = *(const float4*)(in + 4);
    bf16x8 o;
    o[0] = (__bf16)a.x; o[1] = (__bf16)a.y; o[2] = (__bf16)a.z; o[3] = (__bf16)a.w;
    o[4] = (__bf16)c.x; o[5] = (__bf16)c.y; o[6] = (__bf16)c.z; o[7] = (__bf16)c.w;
    *(bf16x8*)out = o;
}

// ---------------------------------------------------------------------------
// 128x128 GEMM core (zero-phase, BK=64, conflict-free slot swizzle) -- used
// by gemm_out (its N=1024 with 256-wide tiles would leave half the CUs idle).
__device__ __forceinline__ void gemm_core(const __bf16* __restrict__ A,
                                          const __bf16* __restrict__ W,
                                          int m0, int n0,
                                          f32x4 (&acc)[4][4]) {
    __shared__ __bf16 As[128 * 64];
    __shared__ __bf16 Bs[128 * 64];
    const int tid  = threadIdx.x;
    const int wid  = tid >> 6;
    const int lane = tid & 63;
    const int ln15 = lane & 15, lg = lane >> 4;
    const int wr = (wid >> 1) * 64;
    const int wc = (wid & 1) * 64;

    const int r0 = tid >> 3;                        // base row 0..31 (+32i)
    const int sc = ((tid & 7) ^ (r0 & 7)) * 8;      // pre-swizzled source col
    char* la = (char*)As + wid * 1024;
    char* lb = (char*)Bs + wid * 1024;
    const int rsw = ln15 & 7;

    for (int k0 = 0; k0 < DM; k0 += 64) {
#pragma unroll
        for (int i = 0; i < 4; ++i) {
            gld16(A + (size_t)(m0 + r0 + i * 32) * DM + k0 + sc, la + i * 4096);
            gld16(W + (size_t)(n0 + r0 + i * 32) * DM + k0 + sc, lb + i * 4096);
        }
        __syncthreads();
#pragma unroll
        for (int kk = 0; kk < 2; ++kk) {
            bf16x8 af[4], bfr[4];
#pragma unroll
            for (int m = 0; m < 4; ++m)
                af[m] = *(const bf16x8*)&As[(wr + m * 16 + ln15) * 64 + (((kk * 4 + lg) ^ rsw) * 8)];
#pragma unroll
            for (int n = 0; n < 4; ++n)
                bfr[n] = *(const bf16x8*)&Bs[(wc + n * 16 + ln15) * 64 + (((kk * 4 + lg) ^ rsw) * 8)];
#pragma unroll
            for (int m = 0; m < 4; ++m)
#pragma unroll
                for (int n = 0; n < 4; ++n)
                    acc[m][n] = __builtin_amdgcn_mfma_f32_16x16x32_bf16(af[m], bfr[n], acc[m][n], 0, 0, 0);
        }
        __syncthreads();
    }
}

// ---------------------------------------------------------------------------
// 128x256 GEMM core, 512 threads / 8 waves (wave grid 2x4, 64x64 each).
// Same zero-phase BK=64 schedule; per K-step one barrier pair now covers 2x
// the output and B-staging bytes/output drop 25% -- amortizes the fixed
// costs that cap the 128x128 core at ~29% MfmaUtil on this K=1024 shape.
__device__ __forceinline__ void gemm_core_wide(const __bf16* __restrict__ A,
                                               const __bf16* __restrict__ W,
                                               int m0, int n0,
                                               f32x4 (&acc)[4][4]) {
    __shared__ __bf16 As[128 * 64];     // 16KB
    __shared__ __bf16 Bs[256 * 64];     // 32KB
    const int tid  = threadIdx.x;
    const int wid  = tid >> 6;
    const int lane = tid & 63;
    const int ln15 = lane & 15, lg = lane >> 4;
    const int wr = (wid >> 2) * 64;
    const int wc = (wid & 3) * 64;

    const int r0 = tid >> 3;                        // base row 0..63 (+64i)
    const int sc = ((tid & 7) ^ (r0 & 7)) * 8;      // pre-swizzled source col
    char* la = (char*)As + wid * 1024;              // dest byte 16*tid (+8192i)
    char* lb = (char*)Bs + wid * 1024;
    const int rsw = ln15 & 7;

    for (int k0 = 0; k0 < DM; k0 += 64) {
#pragma unroll
        for (int i = 0; i < 2; ++i)
            gld16(A + (size_t)(m0 + r0 + i * 64) * DM + k0 + sc, la + i * 8192);
#pragma unroll
        for (int i = 0; i < 4; ++i)
            gld16(W + (size_t)(n0 + r0 + i * 64) * DM + k0 + sc, lb + i * 8192);
        __syncthreads();
#pragma unroll
        for (int kk = 0; kk < 2; ++kk) {
            bf16x8 af[4], bfr[4];
#pragma unroll
            for (int m = 0; m < 4; ++m)
                af[m] = *(const bf16x8*)&As[(wr + m * 16 + ln15) * 64 + (((kk * 4 + lg) ^ rsw) * 8)];
#pragma unroll
            for (int n = 0; n < 4; ++n)
                bfr[n] = *(const bf16x8*)&Bs[(wc + n * 16 + ln15) * 64 + (((kk * 4 + lg) ^ rsw) * 8)];
#pragma unroll
            for (int m = 0; m < 4; ++m)
#pragma unroll
                for (int n = 0; n < 4; ++n)
                    acc[m][n] = __builtin_amdgcn_mfma_f32_16x16x32_bf16(af[m], bfr[n], acc[m][n], 0, 0, 0);
        }
        __syncthreads();
    }
}

// ---------------------------------------------------------------------------
// QKV projection, 128x256 tiles. z=0: Q (pre-scaled 1/8*log2e) -> [bh][s][64];
// z=1: K; z=2: V^T
__global__ __launch_bounds__(512)
void gemm_qkv_kernel(const __bf16* __restrict__ Xb,
                     const __bf16* __restrict__ Wq, const __bf16* __restrict__ Wk,
                     const __bf16* __restrict__ Wv,
                     const float* __restrict__ bq, const float* __restrict__ bk,
                     const float* __restrict__ bv,
                     __bf16* __restrict__ Qb, __bf16* __restrict__ Kb,
                     __bf16* __restrict__ Vt) {
    const int z = blockIdx.z;
    const __bf16* W   = (z == 0) ? Wq : (z == 1) ? Wk : Wv;
    const float* bias = (z == 0) ? bq : (z == 1) ? bk : bv;
    const int m0 = blockIdx.x * 128, n0 = blockIdx.y * 256;

    f32x4 acc[4][4] = {};
    gemm_core_wide(Xb, W, m0, n0, acc);

    const int tid = threadIdx.x, wid = tid >> 6, lane = tid & 63;
    const int ln15 = lane & 15, lg = lane >> 4;
    const int wr = (wid >> 2) * 64, wc = (wid & 3) * 64;
    const float oscl = (z == 0) ? 0.18033688f : 1.0f;  // 0.125 * log2(e)

    if (z < 2) {
        __bf16* out = (z == 0) ? Qb : Kb;
#pragma unroll
        for (int ni = 0; ni < 4; ++ni) {
            int col = n0 + wc + ni * 16 + ln15;
            int h = col >> 6, d = col & 63;
            float bval = bias[col];
#pragma unroll
            for (int mi = 0; mi < 4; ++mi)
#pragma unroll
                for (int r = 0; r < 4; ++r) {
                    int row = m0 + wr + mi * 16 + lg * 4 + r;
                    int b = row >> 11, s = row & 2047;
                    out[(((size_t)(b * H_ + h)) * S_ + s) * DK + d] =
                        (__bf16)((acc[mi][ni][r] + bval) * oscl);
                }
        }
    } else {
#pragma unroll
        for (int ni = 0; ni < 4; ++ni) {
            int col = n0 + wc + ni * 16 + ln15;
            int h = col >> 6, d = col & 63;
            float bval = bias[col];
#pragma unroll
            for (int mi = 0; mi < 4; ++mi)
#pragma unroll
                for (int r = 0; r < 4; ++r) {
                    int row = m0 + wr + mi * 16 + lg * 4 + r;
                    int b = row >> 11, s = row & 2047;
                    Vt[(((size_t)(b * H_ + h)) * DK + d) * S_ + s] =
                        (__bf16)(acc[mi][ni][r] + bval);
                }
        }
    }
}

// ---------------------------------------------------------------------------
__global__ __launch_bounds__(256)
void gemm_out_kernel(const __bf16* __restrict__ Ab, const __bf16* __restrict__ Wo,
                     const float* __restrict__ bo, float* __restrict__ out) {
    const int m0 = blockIdx.x * 128, n0 = blockIdx.y * 128;
    f32x4 acc[4][4] = {};
    gemm_core(Ab, Wo, m0, n0, acc);

    const int tid = threadIdx.x, wid = tid >> 6, lane = tid & 63;
    const int ln15 = lane & 15, lg = lane >> 4;
    const int wr = (wid >> 1) * 64, wc = (wid & 1) * 64;
#pragma unroll
    for (int ni = 0; ni < 4; ++ni) {
        int col = n0 + wc + ni * 16 + ln15;
        float bval = bo[col];
#pragma unroll
        for (int mi = 0; mi < 4; ++mi)
#pragma unroll
            for (int r = 0; r < 4; ++r) {
                int row = m0 + wr + mi * 16 + lg * 4 + r;
                out[(size_t)row * DM + col] = acc[mi][ni][r] + bval;
            }
    }
}

// ---------------------------------------------------------------------------
// Causal flash attention, swapped-QK^T, in-register P (T12), KVBLK=128.
// FIXED m=0 softmax; l-sum via MFMA ones-column; causal pairing {15-p,p};
// XCD-locality grid (64 bh, 8 p): bid%8 = bh%8 -> one bh's K/V lives in one
// XCD's L2 (R18: total -7us). Phase-entry barrier kills the buf0 restage race.
__global__ __launch_bounds__(512)
void attn_kernel(const __bf16* __restrict__ Qb, const __bf16* __restrict__ Kb,
                 const __bf16* __restrict__ Vt, __bf16* __restrict__ AO) {
    __shared__ __bf16 Ks[2][128 * 64];   // [buf][kv][d]   3-bit swizzled (16KB)
    __shared__ __bf16 Vs[2][64 * 128];   // [buf][d][kv]   4-bit swizzled (16KB)

    const int tid = threadIdx.x, wid = tid >> 6, lane = tid & 63;
    const int ln15 = lane & 15, lg = lane >> 4;
    const int bh = blockIdx.x;           // fast dim -> bid%8 = bh%8 = XCD
    const int p  = blockIdx.y;           // pairing index 0..7
    const size_t base = (size_t)bh * (S_ * DK);
    const int b = bh >> 4, h = bh & 15;

    const int krow = wid * 8 + (lane >> 3);               // +0 / +64
    const int kswz = ((lane & 7) ^ (krow & 7)) * 8;
    const int vrow = wid * 4 + (lane >> 4);               // +0 / +32
    const int vswz = ((lane & 15) ^ (vrow & 15)) * 8;
    const int swz  = (ln15 & 7) << 3;

    const __bf16* kgb = Kb + base;
    const __bf16* vgb = Vt + base;

    auto stage = [&](int buf, int kt) {
        char* dk = (char*)Ks + buf * 16384 + wid * 1024;
        char* dv = (char*)Vs + buf * 16384 + wid * 1024;
        gld16(kgb + (size_t)(kt * 128 + krow) * DK + kswz, dk);
        gld16(kgb + (size_t)(kt * 128 + krow + 64) * DK + kswz, dk + 8192);
        gld16(vgb + (size_t)vrow * S_ + kt * 128 + vswz, dv);
        gld16(vgb + (size_t)(vrow + 32) * S_ + kt * 128 + vswz, dv + 8192);
    };

    bf16x8 ones;
#pragma unroll
    for (int j = 0; j < 8; ++j) ones[j] = (__bf16)1.0f;

#pragma unroll
    for (int ph = 0; ph < 2; ++ph) {
        const int qb   = ph ? p : 15 - p;
        const int last = qb;
        const int qr0  = qb * 128 + wid * 16 + ln15;

        bf16x8 qf[2];
        {
            int q0 = qr0;
            qf[0] = *(const bf16x8*)&Qb[base + (size_t)q0 * DK + lg * 8];
            qf[1] = *(const bf16x8*)&Qb[base + (size_t)q0 * DK + 32 + lg * 8];
        }

        f32x4 acc[4] = {};
        f32x4 lacc = {};

        __builtin_amdgcn_s_barrier();
        stage(0, 0);
        asm volatile("s_waitcnt vmcnt(0)" ::: "memory");
        __builtin_amdgcn_s_barrier();
        __builtin_amdgcn_sched_barrier(0);

        for (int kt = 0; kt <= last; ++kt) {
            const int cur = kt & 1;
            if (kt < last) stage(cur ^ 1, kt + 1);

            const __bf16* ksb = &Ks[cur][0];
            const __bf16* vsb = &Vs[cur][0];

            f32x4 z[8] = {};
            __builtin_amdgcn_s_setprio(1);
#pragma unroll
            for (int cb = 0; cb < 8; ++cb)
#pragma unroll
                for (int kk = 0; kk < 2; ++kk) {
                    bf16x8 kf = *(const bf16x8*)&ksb[(cb * 16 + ln15) * 64 + ((kk * 32 + lg * 8) ^ swz)];
                    z[cb] = __builtin_amdgcn_mfma_f32_16x16x32_bf16(kf, qf[kk], z[cb], 0, 0, 0);
                }
            __builtin_amdgcn_s_setprio(0);

            if (kt == last) {
                const int kcb = kt * 128 + lg * 4;
#pragma unroll
                for (int cb = 0; cb < 8; ++cb)
#pragma unroll
                    for (int r = 0; r < 4; ++r)
                        if (kcb + cb * 16 + r > qr0) z[cb][r] = -3e8f;
            }

            uint32_t a0[8], b0[8];
#pragma unroll
            for (int cb = 0; cb < 8; ++cb) {
                float e0 = exp2f(z[cb][0]), e1 = exp2f(z[cb][1]);
                float e2 = exp2f(z[cb][2]), e3 = exp2f(z[cb][3]);
                asm("v_cvt_pk_bf16_f32 %0, %1, %2" : "=v"(a0[cb]) : "v"(e0), "v"(e1));
                asm("v_cvt_pk_bf16_f32 %0, %1, %2" : "=v"(b0[cb]) : "v"(e2), "v"(e3));
            }

            union U8 { uint32_t u[4]; bf16x8 v; };
            bf16x8 pa[4];
#pragma unroll
            for (int ks = 0; ks < 4; ++ks) {
                uint32_t x = a0[2 * ks], y = a0[2 * ks + 1];
                asm("v_permlane32_swap_b32 %0, %1" : "+v"(x), "+v"(y));
                asm("v_permlane16_swap_b32 %0, %1" : "+v"(x), "+v"(y));
                uint32_t p2 = b0[2 * ks], q2 = b0[2 * ks + 1];
                asm("v_permlane32_swap_b32 %0, %1" : "+v"(p2), "+v"(q2));
                asm("v_permlane16_swap_b32 %0, %1" : "+v"(p2), "+v"(q2));
                U8 f; f.u[0] = x; f.u[1] = p2; f.u[2] = y; f.u[3] = q2;
                pa[ks] = f.v;
            }

            __builtin_amdgcn_s_setprio(1);
#pragma unroll
            for (int ks = 0; ks < 4; ++ks) {
                lacc = __builtin_amdgcn_mfma_f32_16x16x32_bf16(pa[ks], ones, lacc, 0, 0, 0);
#pragma unroll
                for (int db = 0; db < 4; ++db) {
                    bf16x8 vf = *(const bf16x8*)&vsb[(db * 16 + ln15) * 128 + (((ks * 4 + lg) ^ ln15) * 8)];
                    acc[db] = __builtin_amdgcn_mfma_f32_16x16x32_bf16(pa[ks], vf, acc[db], 0, 0, 0);
                }
            }
            __builtin_amdgcn_s_setprio(0);

            if (kt < last) {
                asm volatile("s_waitcnt vmcnt(0)" ::: "memory");
                __builtin_amdgcn_s_barrier();
                __builtin_amdgcn_sched_barrier(0);
            }
        }

#pragma unroll
        for (int r = 0; r < 4; ++r) {
            float i0 = 1.f / lacc[r];
            int s0r = qb * 128 + wid * 16 + lg * 4 + r;
#pragma unroll
            for (int db = 0; db < 4; ++db)
                AO[((size_t)(b * S_ + s0r)) * DM + h * DK + db * 16 + ln15] = (__bf16)(acc[db][r] * i0);
        }
    }
}

// ---------------------------------------------------------------------------
extern "C" void kernel_launch(void* const* d_in, const int* in_sizes, int n_in,
                              void* d_out, int out_size, void* d_ws, size_t ws_size,
                              hipStream_t stream) {
    const float* x  = (const float*)d_in[0];
    const float* Wq = (const float*)d_in[2];
    const float* bq = (const float*)d_in[3];
    const float* Wk = (const float*)d_in[4];
    const float* bk = (const float*)d_in[5];
    const float* Wv = (const float*)d_in[6];
    const float* bv = (const float*)d_in[7];
    const float* Wo = (const float*)d_in[8];
    const float* bo = (const float*)d_in[9];
    float* out = (float*)d_out;

    char* ws = (char*)d_ws;
    __bf16* xb  = (__bf16*)ws;                       // reused as attn out
    __bf16* wqb = (__bf16*)(ws + 16777216);
    __bf16* wkb = wqb + 1048576;
    __bf16* wvb = wkb + 1048576;
    __bf16* wob = wvb + 1048576;
    __bf16* Qb  = (__bf16*)(ws + 25165824);
    __bf16* Kb  = Qb + 8388608;
    __bf16* Vt  = Kb + 8388608;
    __bf16* AO  = xb;

    cvt_all<<<6144, 256, 0, stream>>>(x, Wq, Wk, Wv, Wo, xb, wqb);

    gemm_qkv_kernel<<<dim3(64, 4, 3), 512, 0, stream>>>(xb, wqb, wkb, wvb,
                                                        bq, bk, bv, Qb, Kb, Vt);
    attn_kernel<<<dim3(64, 8), 512, 0, stream>>>(Qb, Kb, Vt, AO);
    gemm_out_kernel<<<dim3(64, 8), 256, 0, stream>>>(AO, wob, bo, out);
}

// Round 20
// 169.126 us; speedup vs baseline: 1.0296x; 1.0296x over previous
//
#include <hip/hip_runtime.h>
#include <hip/hip_bf16.h>
#include <stdint.h>

typedef __bf16 bf16x8 __attribute__((ext_vector_type(8)));
typedef float  f32x4  __attribute__((ext_vector_type(4)));

#define B_   4
#define S_   2048
#define DM   1024
#define H_   16
#define DK   64
#define M_TOT 8192

// ---------------------------------------------------------------------------
__device__ __forceinline__ void gld16(const __bf16* g, char* l) {
    __builtin_amdgcn_global_load_lds(
        (const __attribute__((address_space(1))) void*)g,
        (__attribute__((address_space(3))) void*)l,
        16, 0, 0);
}

// ---------------------------------------------------------------------------
// One dispatch: x (8.4M elems) then 4 weight matrices (4x1M) -> bf16.
__global__ __launch_bounds__(256)
void cvt_all(const float* __restrict__ x,
             const float* __restrict__ w0, const float* __restrict__ w1,
             const float* __restrict__ w2, const float* __restrict__ w3,
             __bf16* __restrict__ xb, __bf16* __restrict__ wb) {
    int i = (blockIdx.x * 256 + threadIdx.x) * 8;
    const float* in;
    __bf16* out;
    if (i < M_TOT * DM) {
        in = x + i; out = xb + i;
    } else {
        int j = i - M_TOT * DM;          // 0 .. 4*1048576-1
        int w = j >> 20;
        const float* ws4[4] = {w0, w1, w2, w3};
        in = ws4[w] + (j & 1048575); out = wb + j;
    }
    float4 a = *(const float4*)in;
    float4 c = *(const float4*)(in + 4);
    bf16x8 o;
    o[0] = (__bf16)a.x; o[1] = (__bf16)a.y; o[2] = (__bf16)a.z; o[3] = (__bf16)a.w;
    o[4] = (__bf16)c.x; o[5] = (__bf16)c.y; o[6] = (__bf16)c.z; o[7] = (__bf16)c.w;
    *(bf16x8*)out = o;
}

// ---------------------------------------------------------------------------
// 128x128 GEMM core: zero-phase, BK=64, conflict-free slot swizzle
// (R18-measured best: qkv 74.3us, MfmaUtil 29%). Explicit dbuf (R14) and
// wider tiles (R19) both regressed -- occupancy trades lose in this family.
__device__ __forceinline__ void gemm_core(const __bf16* __restrict__ A,
                                          const __bf16* __restrict__ W,
                                          int m0, int n0,
                                          f32x4 (&acc)[4][4]) {
    __shared__ __bf16 As[128 * 64];
    __shared__ __bf16 Bs[128 * 64];
    const int tid  = threadIdx.x;
    const int wid  = tid >> 6;
    const int lane = tid & 63;
    const int ln15 = lane & 15, lg = lane >> 4;
    const int wr = (wid >> 1) * 64;
    const int wc = (wid & 1) * 64;

    const int r0 = tid >> 3;                        // base row 0..31 (+32i)
    const int sc = ((tid & 7) ^ (r0 & 7)) * 8;      // pre-swizzled source col
    char* la = (char*)As + wid * 1024;
    char* lb = (char*)Bs + wid * 1024;
    const int rsw = ln15 & 7;

    for (int k0 = 0; k0 < DM; k0 += 64) {
#pragma unroll
        for (int i = 0; i < 4; ++i) {
            gld16(A + (size_t)(m0 + r0 + i * 32) * DM + k0 + sc, la + i * 4096);
            gld16(W + (size_t)(n0 + r0 + i * 32) * DM + k0 + sc, lb + i * 4096);
        }
        __syncthreads();
#pragma unroll
        for (int kk = 0; kk < 2; ++kk) {
            bf16x8 af[4], bfr[4];
#pragma unroll
            for (int m = 0; m < 4; ++m)
                af[m] = *(const bf16x8*)&As[(wr + m * 16 + ln15) * 64 + (((kk * 4 + lg) ^ rsw) * 8)];
#pragma unroll
            for (int n = 0; n < 4; ++n)
                bfr[n] = *(const bf16x8*)&Bs[(wc + n * 16 + ln15) * 64 + (((kk * 4 + lg) ^ rsw) * 8)];
#pragma unroll
            for (int m = 0; m < 4; ++m)
#pragma unroll
                for (int n = 0; n < 4; ++n)
                    acc[m][n] = __builtin_amdgcn_mfma_f32_16x16x32_bf16(af[m], bfr[n], acc[m][n], 0, 0, 0);
        }
        __syncthreads();
    }
}

// ---------------------------------------------------------------------------
// QKV projection. z=0: Q (pre-scaled by 1/8*log2e) -> [bh][s][64]; z=1: K; z=2: V^T
__global__ __launch_bounds__(256)
void gemm_qkv_kernel(const __bf16* __restrict__ Xb,
                     const __bf16* __restrict__ Wq, const __bf16* __restrict__ Wk,
                     const __bf16* __restrict__ Wv,
                     const float* __restrict__ bq, const float* __restrict__ bk,
                     const float* __restrict__ bv,
                     __bf16* __restrict__ Qb, __bf16* __restrict__ Kb,
                     __bf16* __restrict__ Vt) {
    const int z = blockIdx.z;
    const __bf16* W   = (z == 0) ? Wq : (z == 1) ? Wk : Wv;
    const float* bias = (z == 0) ? bq : (z == 1) ? bk : bv;
    const int m0 = blockIdx.x * 128, n0 = blockIdx.y * 128;

    f32x4 acc[4][4] = {};
    gemm_core(Xb, W, m0, n0, acc);

    const int tid = threadIdx.x, wid = tid >> 6, lane = tid & 63;
    const int ln15 = lane & 15, lg = lane >> 4;
    const int wr = (wid >> 1) * 64, wc = (wid & 1) * 64;
    const float oscl = (z == 0) ? 0.18033688f : 1.0f;  // 0.125 * log2(e)

    if (z < 2) {
        __bf16* out = (z == 0) ? Qb : Kb;
#pragma unroll
        for (int ni = 0; ni < 4; ++ni) {
            int col = n0 + wc + ni * 16 + ln15;
            int h = col >> 6, d = col & 63;
            float bval = bias[col];
#pragma unroll
            for (int mi = 0; mi < 4; ++mi)
#pragma unroll
                for (int r = 0; r < 4; ++r) {
                    int row = m0 + wr + mi * 16 + lg * 4 + r;
                    int b = row >> 11, s = row & 2047;
                    out[(((size_t)(b * H_ + h)) * S_ + s) * DK + d] =
                        (__bf16)((acc[mi][ni][r] + bval) * oscl);
                }
        }
    } else {
#pragma unroll
        for (int ni = 0; ni < 4; ++ni) {
            int col = n0 + wc + ni * 16 + ln15;
            int h = col >> 6, d = col & 63;
            float bval = bias[col];
#pragma unroll
            for (int mi = 0; mi < 4; ++mi)
#pragma unroll
                for (int r = 0; r < 4; ++r) {
                    int row = m0 + wr + mi * 16 + lg * 4 + r;
                    int b = row >> 11, s = row & 2047;
                    Vt[(((size_t)(b * H_ + h)) * DK + d) * S_ + s] =
                        (__bf16)(acc[mi][ni][r] + bval);
                }
        }
    }
}

// ---------------------------------------------------------------------------
__global__ __launch_bounds__(256)
void gemm_out_kernel(const __bf16* __restrict__ Ab, const __bf16* __restrict__ Wo,
                     const float* __restrict__ bo, float* __restrict__ out) {
    const int m0 = blockIdx.x * 128, n0 = blockIdx.y * 128;
    f32x4 acc[4][4] = {};
    gemm_core(Ab, Wo, m0, n0, acc);

    const int tid = threadIdx.x, wid = tid >> 6, lane = tid & 63;
    const int ln15 = lane & 15, lg = lane >> 4;
    const int wr = (wid >> 1) * 64, wc = (wid & 1) * 64;
#pragma unroll
    for (int ni = 0; ni < 4; ++ni) {
        int col = n0 + wc + ni * 16 + ln15;
        float bval = bo[col];
#pragma unroll
        for (int mi = 0; mi < 4; ++mi)
#pragma unroll
            for (int r = 0; r < 4; ++r) {
                int row = m0 + wr + mi * 16 + lg * 4 + r;
                out[(size_t)row * DM + col] = acc[mi][ni][r] + bval;
            }
    }
}

// ---------------------------------------------------------------------------
// Causal flash attention, swapped-QK^T, in-register P (T12), KVBLK=128.
// FIXED m=0 softmax; l-sum via MFMA ones-column; causal pairing {15-p,p};
// XCD-locality grid (64 bh, 8 p): bid%8 = bh%8 -> one bh's K/V lives in one
// XCD's L2. Phase-entry barrier kills the buf0 restage race.
__global__ __launch_bounds__(512)
void attn_kernel(const __bf16* __restrict__ Qb, const __bf16* __restrict__ Kb,
                 const __bf16* __restrict__ Vt, __bf16* __restrict__ AO) {
    __shared__ __bf16 Ks[2][128 * 64];   // [buf][kv][d]   3-bit swizzled (16KB)
    __shared__ __bf16 Vs[2][64 * 128];   // [buf][d][kv]   4-bit swizzled (16KB)

    const int tid = threadIdx.x, wid = tid >> 6, lane = tid & 63;
    const int ln15 = lane & 15, lg = lane >> 4;
    const int bh = blockIdx.x;           // fast dim -> bid%8 = bh%8 = XCD
    const int p  = blockIdx.y;           // pairing index 0..7
    const size_t base = (size_t)bh * (S_ * DK);
    const int b = bh >> 4, h = bh & 15;

    const int krow = wid * 8 + (lane >> 3);               // +0 / +64
    const int kswz = ((lane & 7) ^ (krow & 7)) * 8;
    const int vrow = wid * 4 + (lane >> 4);               // +0 / +32
    const int vswz = ((lane & 15) ^ (vrow & 15)) * 8;
    const int swz  = (ln15 & 7) << 3;

    const __bf16* kgb = Kb + base;
    const __bf16* vgb = Vt + base;

    auto stage = [&](int buf, int kt) {
        char* dk = (char*)Ks + buf * 16384 + wid * 1024;
        char* dv = (char*)Vs + buf * 16384 + wid * 1024;
        gld16(kgb + (size_t)(kt * 128 + krow) * DK + kswz, dk);
        gld16(kgb + (size_t)(kt * 128 + krow + 64) * DK + kswz, dk + 8192);
        gld16(vgb + (size_t)vrow * S_ + kt * 128 + vswz, dv);
        gld16(vgb + (size_t)(vrow + 32) * S_ + kt * 128 + vswz, dv + 8192);
    };

    bf16x8 ones;
#pragma unroll
    for (int j = 0; j < 8; ++j) ones[j] = (__bf16)1.0f;

#pragma unroll
    for (int ph = 0; ph < 2; ++ph) {
        const int qb   = ph ? p : 15 - p;
        const int last = qb;
        const int qr0  = qb * 128 + wid * 16 + ln15;

        bf16x8 qf[2];
        {
            int q0 = qr0;
            qf[0] = *(const bf16x8*)&Qb[base + (size_t)q0 * DK + lg * 8];
            qf[1] = *(const bf16x8*)&Qb[base + (size_t)q0 * DK + 32 + lg * 8];
        }

        f32x4 acc[4] = {};
        f32x4 lacc = {};

        __builtin_amdgcn_s_barrier();
        stage(0, 0);
        asm volatile("s_waitcnt vmcnt(0)" ::: "memory");
        __builtin_amdgcn_s_barrier();
        __builtin_amdgcn_sched_barrier(0);

        for (int kt = 0; kt <= last; ++kt) {
            const int cur = kt & 1;
            if (kt < last) stage(cur ^ 1, kt + 1);

            const __bf16* ksb = &Ks[cur][0];
            const __bf16* vsb = &Vs[cur][0];

            f32x4 z[8] = {};
            __builtin_amdgcn_s_setprio(1);
#pragma unroll
            for (int cb = 0; cb < 8; ++cb)
#pragma unroll
                for (int kk = 0; kk < 2; ++kk) {
                    bf16x8 kf = *(const bf16x8*)&ksb[(cb * 16 + ln15) * 64 + ((kk * 32 + lg * 8) ^ swz)];
                    z[cb] = __builtin_amdgcn_mfma_f32_16x16x32_bf16(kf, qf[kk], z[cb], 0, 0, 0);
                }
            __builtin_amdgcn_s_setprio(0);

            if (kt == last) {
                const int kcb = kt * 128 + lg * 4;
#pragma unroll
                for (int cb = 0; cb < 8; ++cb)
#pragma unroll
                    for (int r = 0; r < 4; ++r)
                        if (kcb + cb * 16 + r > qr0) z[cb][r] = -3e8f;
            }

            uint32_t a0[8], b0[8];
#pragma unroll
            for (int cb = 0; cb < 8; ++cb) {
                float e0 = exp2f(z[cb][0]), e1 = exp2f(z[cb][1]);
                float e2 = exp2f(z[cb][2]), e3 = exp2f(z[cb][3]);
                asm("v_cvt_pk_bf16_f32 %0, %1, %2" : "=v"(a0[cb]) : "v"(e0), "v"(e1));
                asm("v_cvt_pk_bf16_f32 %0, %1, %2" : "=v"(b0[cb]) : "v"(e2), "v"(e3));
            }

            union U8 { uint32_t u[4]; bf16x8 v; };
            bf16x8 pa[4];
#pragma unroll
            for (int ks = 0; ks < 4; ++ks) {
                uint32_t x = a0[2 * ks], y = a0[2 * ks + 1];
                asm("v_permlane32_swap_b32 %0, %1" : "+v"(x), "+v"(y));
                asm("v_permlane16_swap_b32 %0, %1" : "+v"(x), "+v"(y));
                uint32_t p2 = b0[2 * ks], q2 = b0[2 * ks + 1];
                asm("v_permlane32_swap_b32 %0, %1" : "+v"(p2), "+v"(q2));
                asm("v_permlane16_swap_b32 %0, %1" : "+v"(p2), "+v"(q2));
                U8 f; f.u[0] = x; f.u[1] = p2; f.u[2] = y; f.u[3] = q2;
                pa[ks] = f.v;
            }

            __builtin_amdgcn_s_setprio(1);
#pragma unroll
            for (int ks = 0; ks < 4; ++ks) {
                lacc = __builtin_amdgcn_mfma_f32_16x16x32_bf16(pa[ks], ones, lacc, 0, 0, 0);
#pragma unroll
                for (int db = 0; db < 4; ++db) {
                    bf16x8 vf = *(const bf16x8*)&vsb[(db * 16 + ln15) * 128 + (((ks * 4 + lg) ^ ln15) * 8)];
                    acc[db] = __builtin_amdgcn_mfma_f32_16x16x32_bf16(pa[ks], vf, acc[db], 0, 0, 0);
                }
            }
            __builtin_amdgcn_s_setprio(0);

            if (kt < last) {
                asm volatile("s_waitcnt vmcnt(0)" ::: "memory");
                __builtin_amdgcn_s_barrier();
                __builtin_amdgcn_sched_barrier(0);
            }
        }

#pragma unroll
        for (int r = 0; r < 4; ++r) {
            float i0 = 1.f / lacc[r];
            int s0r = qb * 128 + wid * 16 + lg * 4 + r;
#pragma unroll
            for (int db = 0; db < 4; ++db)
                AO[((size_t)(b * S_ + s0r)) * DM + h * DK + db * 16 + ln15] = (__bf16)(acc[db][r] * i0);
        }
    }
}

// ---------------------------------------------------------------------------
extern "C" void kernel_launch(void* const* d_in, const int* in_sizes, int n_in,
                              void* d_out, int out_size, void* d_ws, size_t ws_size,
                              hipStream_t stream) {
    const float* x  = (const float*)d_in[0];
    const float* Wq = (const float*)d_in[2];
    const float* bq = (const float*)d_in[3];
    const float* Wk = (const float*)d_in[4];
    const float* bk = (const float*)d_in[5];
    const float* Wv = (const float*)d_in[6];
    const float* bv = (const float*)d_in[7];
    const float* Wo = (const float*)d_in[8];
    const float* bo = (const float*)d_in[9];
    float* out = (float*)d_out;

    char* ws = (char*)d_ws;
    __bf16* xb  = (__bf16*)ws;                       // reused as attn out
    __bf16* wqb = (__bf16*)(ws + 16777216);
    __bf16* wkb = wqb + 1048576;
    __bf16* wvb = wkb + 1048576;
    __bf16* wob = wvb + 1048576;
    __bf16* Qb  = (__bf16*)(ws + 25165824);
    __bf16* Kb  = Qb + 8388608;
    __bf16* Vt  = Kb + 8388608;
    __bf16* AO  = xb;

    cvt_all<<<6144, 256, 0, stream>>>(x, Wq, Wk, Wv, Wo, xb, wqb);

    gemm_qkv_kernel<<<dim3(64, 8, 3), 256, 0, stream>>>(xb, wqb, wkb, wvb,
                                                        bq, bk, bv, Qb, Kb, Vt);
    attn_kernel<<<dim3(64, 8), 512, 0, stream>>>(Qb, Kb, Vt, AO);
    gemm_out_kernel<<<dim3(64, 8), 256, 0, stream>>>(AO, wob, bo, out);
}

// Round 21
// 167.745 us; speedup vs baseline: 1.0381x; 1.0082x over previous
//
#include <hip/hip_runtime.h>
#include <hip/hip_bf16.h>
#include <stdint.h>

typedef __bf16 bf16x8 __attribute__((ext_vector_type(8)));
typedef float  f32x4  __attribute__((ext_vector_type(4)));

#define B_   4
#define S_   2048
#define DM   1024
#define H_   16
#define DK   64
#define M_TOT 8192

// ---------------------------------------------------------------------------
__device__ __forceinline__ void gld16(const __bf16* g, char* l) {
    __builtin_amdgcn_global_load_lds(
        (const __attribute__((address_space(1))) void*)g,
        (__attribute__((address_space(3))) void*)l,
        16, 0, 0);
}

// ---------------------------------------------------------------------------
// One dispatch: x (8.4M elems) then 4 weight matrices (4x1M) -> bf16.
__global__ __launch_bounds__(256)
void cvt_all(const float* __restrict__ x,
             const float* __restrict__ w0, const float* __restrict__ w1,
             const float* __restrict__ w2, const float* __restrict__ w3,
             __bf16* __restrict__ xb, __bf16* __restrict__ wb) {
    int i = (blockIdx.x * 256 + threadIdx.x) * 8;
    const float* in;
    __bf16* out;
    if (i < M_TOT * DM) {
        in = x + i; out = xb + i;
    } else {
        int j = i - M_TOT * DM;          // 0 .. 4*1048576-1
        int w = j >> 20;
        const float* ws4[4] = {w0, w1, w2, w3};
        in = ws4[w] + (j & 1048575); out = wb + j;
    }
    float4 a = *(const float4*)in;
    float4 c = *(const float4*)(in + 4);
    bf16x8 o;
    o[0] = (__bf16)a.x; o[1] = (__bf16)a.y; o[2] = (__bf16)a.z; o[3] = (__bf16)a.w;
    o[4] = (__bf16)c.x; o[5] = (__bf16)c.y; o[6] = (__bf16)c.z; o[7] = (__bf16)c.w;
    *(bf16x8*)out = o;
}

// ---------------------------------------------------------------------------
// 128x128 GEMM core: zero-phase, BK=64, conflict-free slot swizzle.
// SADDR-form staging: per-lane 32-bit offsets precomputed once; per K-step
// the base pointer A+k0 advances uniformly (SALU) -- removes the per-step
// per-lane 64-bit address chains (~24 VALU/step) behind VALUBusy=38%.
__device__ __forceinline__ void gemm_core(const __bf16* __restrict__ A,
                                          const __bf16* __restrict__ W,
                                          int m0, int n0,
                                          f32x4 (&acc)[4][4]) {
    __shared__ __bf16 As[128 * 64];
    __shared__ __bf16 Bs[128 * 64];
    const int tid  = threadIdx.x;
    const int wid  = tid >> 6;
    const int lane = tid & 63;
    const int ln15 = lane & 15, lg = lane >> 4;
    const int wr = (wid >> 1) * 64;
    const int wc = (wid & 1) * 64;

    const int r0 = tid >> 3;                        // base row 0..31 (+32i)
    const int sc = ((tid & 7) ^ (r0 & 7)) * 8;      // pre-swizzled source col
    uint32_t aoff[4], boff[4];
#pragma unroll
    for (int i = 0; i < 4; ++i) {
        aoff[i] = (uint32_t)((m0 + r0 + i * 32) * DM + sc);
        boff[i] = (uint32_t)((n0 + r0 + i * 32) * DM + sc);
    }
    char* la = (char*)As + wid * 1024;
    char* lb = (char*)Bs + wid * 1024;
    const int rsw = ln15 & 7;

    for (int k0 = 0; k0 < DM; k0 += 64) {
        const __bf16* Ak = A + k0;                  // uniform (SALU advance)
        const __bf16* Wk = W + k0;
#pragma unroll
        for (int i = 0; i < 4; ++i) {
            gld16(Ak + aoff[i], la + i * 4096);
            gld16(Wk + boff[i], lb + i * 4096);
        }
        __syncthreads();
#pragma unroll
        for (int kk = 0; kk < 2; ++kk) {
            bf16x8 af[4], bfr[4];
#pragma unroll
            for (int m = 0; m < 4; ++m)
                af[m] = *(const bf16x8*)&As[(wr + m * 16 + ln15) * 64 + (((kk * 4 + lg) ^ rsw) * 8)];
#pragma unroll
            for (int n = 0; n < 4; ++n)
                bfr[n] = *(const bf16x8*)&Bs[(wc + n * 16 + ln15) * 64 + (((kk * 4 + lg) ^ rsw) * 8)];
#pragma unroll
            for (int m = 0; m < 4; ++m)
#pragma unroll
                for (int n = 0; n < 4; ++n)
                    acc[m][n] = __builtin_amdgcn_mfma_f32_16x16x32_bf16(af[m], bfr[n], acc[m][n], 0, 0, 0);
        }
        __syncthreads();
    }
}

// ---------------------------------------------------------------------------
// QKV projection. z=0: Q (pre-scaled by 1/8*log2e) -> [bh][s][64]; z=1: K; z=2: V^T
__global__ __launch_bounds__(256)
void gemm_qkv_kernel(const __bf16* __restrict__ Xb,
                     const __bf16* __restrict__ Wq, const __bf16* __restrict__ Wk,
                     const __bf16* __restrict__ Wv,
                     const float* __restrict__ bq, const float* __restrict__ bk,
                     const float* __restrict__ bv,
                     __bf16* __restrict__ Qb, __bf16* __restrict__ Kb,
                     __bf16* __restrict__ Vt) {
    const int z = blockIdx.z;
    const __bf16* W   = (z == 0) ? Wq : (z == 1) ? Wk : Wv;
    const float* bias = (z == 0) ? bq : (z == 1) ? bk : bv;
    const int m0 = blockIdx.x * 128, n0 = blockIdx.y * 128;

    f32x4 acc[4][4] = {};
    gemm_core(Xb, W, m0, n0, acc);

    const int tid = threadIdx.x, wid = tid >> 6, lane = tid & 63;
    const int ln15 = lane & 15, lg = lane >> 4;
    const int wr = (wid >> 1) * 64, wc = (wid & 1) * 64;
    const float oscl = (z == 0) ? 0.18033688f : 1.0f;  // 0.125 * log2(e)

    if (z < 2) {
        __bf16* out = (z == 0) ? Qb : Kb;
#pragma unroll
        for (int ni = 0; ni < 4; ++ni) {
            int col = n0 + wc + ni * 16 + ln15;
            int h = col >> 6, d = col & 63;
            float bval = bias[col];
#pragma unroll
            for (int mi = 0; mi < 4; ++mi)
#pragma unroll
                for (int r = 0; r < 4; ++r) {
                    int row = m0 + wr + mi * 16 + lg * 4 + r;
                    int b = row >> 11, s = row & 2047;
                    out[(((size_t)(b * H_ + h)) * S_ + s) * DK + d] =
                        (__bf16)((acc[mi][ni][r] + bval) * oscl);
                }
        }
    } else {
#pragma unroll
        for (int ni = 0; ni < 4; ++ni) {
            int col = n0 + wc + ni * 16 + ln15;
            int h = col >> 6, d = col & 63;
            float bval = bias[col];
#pragma unroll
            for (int mi = 0; mi < 4; ++mi)
#pragma unroll
                for (int r = 0; r < 4; ++r) {
                    int row = m0 + wr + mi * 16 + lg * 4 + r;
                    int b = row >> 11, s = row & 2047;
                    Vt[(((size_t)(b * H_ + h)) * DK + d) * S_ + s] =
                        (__bf16)(acc[mi][ni][r] + bval);
                }
        }
    }
}

// ---------------------------------------------------------------------------
__global__ __launch_bounds__(256)
void gemm_out_kernel(const __bf16* __restrict__ Ab, const __bf16* __restrict__ Wo,
                     const float* __restrict__ bo, float* __restrict__ out) {
    const int m0 = blockIdx.x * 128, n0 = blockIdx.y * 128;
    f32x4 acc[4][4] = {};
    gemm_core(Ab, Wo, m0, n0, acc);

    const int tid = threadIdx.x, wid = tid >> 6, lane = tid & 63;
    const int ln15 = lane & 15, lg = lane >> 4;
    const int wr = (wid >> 1) * 64, wc = (wid & 1) * 64;
#pragma unroll
    for (int ni = 0; ni < 4; ++ni) {
        int col = n0 + wc + ni * 16 + ln15;
        float bval = bo[col];
#pragma unroll
        for (int mi = 0; mi < 4; ++mi)
#pragma unroll
            for (int r = 0; r < 4; ++r) {
                int row = m0 + wr + mi * 16 + lg * 4 + r;
                out[(size_t)row * DM + col] = acc[mi][ni][r] + bval;
            }
    }
}

// ---------------------------------------------------------------------------
// Causal flash attention, swapped-QK^T, in-register P (T12), KVBLK=128.
// FIXED m=0 softmax; l-sum via MFMA ones-column; causal pairing {15-p,p};
// XCD-locality grid (64 bh, 8 p). Stage uses saddr-form addressing:
// uniform base kgb + kt*128*DK, loop-invariant 32-bit lane offsets.
__global__ __launch_bounds__(512)
void attn_kernel(const __bf16* __restrict__ Qb, const __bf16* __restrict__ Kb,
                 const __bf16* __restrict__ Vt, __bf16* __restrict__ AO) {
    __shared__ __bf16 Ks[2][128 * 64];   // [buf][kv][d]   3-bit swizzled (16KB)
    __shared__ __bf16 Vs[2][64 * 128];   // [buf][d][kv]   4-bit swizzled (16KB)

    const int tid = threadIdx.x, wid = tid >> 6, lane = tid & 63;
    const int ln15 = lane & 15, lg = lane >> 4;
    const int bh = blockIdx.x;           // fast dim -> bid%8 = bh%8 = XCD
    const int p  = blockIdx.y;           // pairing index 0..7
    const size_t base = (size_t)bh * (S_ * DK);
    const int b = bh >> 4, h = bh & 15;

    const int krow = wid * 8 + (lane >> 3);               // +0 / +64
    const int kswz = ((lane & 7) ^ (krow & 7)) * 8;
    const int vrow = wid * 4 + (lane >> 4);               // +0 / +32
    const int vswz = ((lane & 15) ^ (vrow & 15)) * 8;
    const int swz  = (ln15 & 7) << 3;

    // loop-invariant 32-bit lane offsets (saddr-form staging)
    const uint32_t ko1 = (uint32_t)(krow * DK + kswz);
    const uint32_t ko2 = (uint32_t)((krow + 64) * DK + kswz);
    const uint32_t vo1 = (uint32_t)(vrow * S_ + vswz);
    const uint32_t vo2 = (uint32_t)((vrow + 32) * S_ + vswz);

    const __bf16* kgb = Kb + base;
    const __bf16* vgb = Vt + base;

    auto stage = [&](int buf, int kt) {
        char* dk = (char*)Ks + buf * 16384 + wid * 1024;
        char* dv = (char*)Vs + buf * 16384 + wid * 1024;
        const __bf16* kk_ = kgb + kt * (128 * DK);   // uniform
        const __bf16* vv_ = vgb + kt * 128;          // uniform
        gld16(kk_ + ko1, dk);
        gld16(kk_ + ko2, dk + 8192);
        gld16(vv_ + vo1, dv);
        gld16(vv_ + vo2, dv + 8192);
    };

    bf16x8 ones;
#pragma unroll
    for (int j = 0; j < 8; ++j) ones[j] = (__bf16)1.0f;

#pragma unroll
    for (int ph = 0; ph < 2; ++ph) {
        const int qb   = ph ? p : 15 - p;
        const int last = qb;
        const int qr0  = qb * 128 + wid * 16 + ln15;

        bf16x8 qf[2];
        {
            int q0 = qr0;
            qf[0] = *(const bf16x8*)&Qb[base + (size_t)q0 * DK + lg * 8];
            qf[1] = *(const bf16x8*)&Qb[base + (size_t)q0 * DK + 32 + lg * 8];
        }

        f32x4 acc[4] = {};
        f32x4 lacc = {};

        __builtin_amdgcn_s_barrier();
        stage(0, 0);
        asm volatile("s_waitcnt vmcnt(0)" ::: "memory");
        __builtin_amdgcn_s_barrier();
        __builtin_amdgcn_sched_barrier(0);

        for (int kt = 0; kt <= last; ++kt) {
            const int cur = kt & 1;
            if (kt < last) stage(cur ^ 1, kt + 1);

            const __bf16* ksb = &Ks[cur][0];
            const __bf16* vsb = &Vs[cur][0];

            f32x4 z[8] = {};
            __builtin_amdgcn_s_setprio(1);
#pragma unroll
            for (int cb = 0; cb < 8; ++cb)
#pragma unroll
                for (int kk = 0; kk < 2; ++kk) {
                    bf16x8 kf = *(const bf16x8*)&ksb[(cb * 16 + ln15) * 64 + ((kk * 32 + lg * 8) ^ swz)];
                    z[cb] = __builtin_amdgcn_mfma_f32_16x16x32_bf16(kf, qf[kk], z[cb], 0, 0, 0);
                }
            __builtin_amdgcn_s_setprio(0);

            if (kt == last) {
                const int kcb = kt * 128 + lg * 4;
#pragma unroll
                for (int cb = 0; cb < 8; ++cb)
#pragma unroll
                    for (int r = 0; r < 4; ++r)
                        if (kcb + cb * 16 + r > qr0) z[cb][r] = -3e8f;
            }

            uint32_t a0[8], b0[8];
#pragma unroll
            for (int cb = 0; cb < 8; ++cb) {
                float e0 = exp2f(z[cb][0]), e1 = exp2f(z[cb][1]);
                float e2 = exp2f(z[cb][2]), e3 = exp2f(z[cb][3]);
                asm("v_cvt_pk_bf16_f32 %0, %1, %2" : "=v"(a0[cb]) : "v"(e0), "v"(e1));
                asm("v_cvt_pk_bf16_f32 %0, %1, %2" : "=v"(b0[cb]) : "v"(e2), "v"(e3));
            }

            union U8 { uint32_t u[4]; bf16x8 v; };
            bf16x8 pa[4];
#pragma unroll
            for (int ks = 0; ks < 4; ++ks) {
                uint32_t x = a0[2 * ks], y = a0[2 * ks + 1];
                asm("v_permlane32_swap_b32 %0, %1" : "+v"(x), "+v"(y));
                asm("v_permlane16_swap_b32 %0, %1" : "+v"(x), "+v"(y));
                uint32_t p2 = b0[2 * ks], q2 = b0[2 * ks + 1];
                asm("v_permlane32_swap_b32 %0, %1" : "+v"(p2), "+v"(q2));
                asm("v_permlane16_swap_b32 %0, %1" : "+v"(p2), "+v"(q2));
                U8 f; f.u[0] = x; f.u[1] = p2; f.u[2] = y; f.u[3] = q2;
                pa[ks] = f.v;
            }

            __builtin_amdgcn_s_setprio(1);
#pragma unroll
            for (int ks = 0; ks < 4; ++ks) {
                lacc = __builtin_amdgcn_mfma_f32_16x16x32_bf16(pa[ks], ones, lacc, 0, 0, 0);
#pragma unroll
                for (int db = 0; db < 4; ++db) {
                    bf16x8 vf = *(const bf16x8*)&vsb[(db * 16 + ln15) * 128 + (((ks * 4 + lg) ^ ln15) * 8)];
                    acc[db] = __builtin_amdgcn_mfma_f32_16x16x32_bf16(pa[ks], vf, acc[db], 0, 0, 0);
                }
            }
            __builtin_amdgcn_s_setprio(0);

            if (kt < last) {
                asm volatile("s_waitcnt vmcnt(0)" ::: "memory");
                __builtin_amdgcn_s_barrier();
                __builtin_amdgcn_sched_barrier(0);
            }
        }

#pragma unroll
        for (int r = 0; r < 4; ++r) {
            float i0 = 1.f / lacc[r];
            int s0r = qb * 128 + wid * 16 + lg * 4 + r;
#pragma unroll
            for (int db = 0; db < 4; ++db)
                AO[((size_t)(b * S_ + s0r)) * DM + h * DK + db * 16 + ln15] = (__bf16)(acc[db][r] * i0);
        }
    }
}

// ---------------------------------------------------------------------------
extern "C" void kernel_launch(void* const* d_in, const int* in_sizes, int n_in,
                              void* d_out, int out_size, void* d_ws, size_t ws_size,
                              hipStream_t stream) {
    const float* x  = (const float*)d_in[0];
    const float* Wq = (const float*)d_in[2];
    const float* bq = (const float*)d_in[3];
    const float* Wk = (const float*)d_in[4];
    const float* bk = (const float*)d_in[5];
    const float* Wv = (const float*)d_in[6];
    const float* bv = (const float*)d_in[7];
    const float* Wo = (const float*)d_in[8];
    const float* bo = (const float*)d_in[9];
    float* out = (float*)d_out;

    char* ws = (char*)d_ws;
    __bf16* xb  = (__bf16*)ws;                       // reused as attn out
    __bf16* wqb = (__bf16*)(ws + 16777216);
    __bf16* wkb = wqb + 1048576;
    __bf16* wvb = wkb + 1048576;
    __bf16* wob = wvb + 1048576;
    __bf16* Qb  = (__bf16*)(ws + 25165824);
    __bf16* Kb  = Qb + 8388608;
    __bf16* Vt  = Kb + 8388608;
    __bf16* AO  = xb;

    cvt_all<<<6144, 256, 0, stream>>>(x, Wq, Wk, Wv, Wo, xb, wqb);

    gemm_qkv_kernel<<<dim3(64, 8, 3), 256, 0, stream>>>(xb, wqb, wkb, wvb,
                                                        bq, bk, bv, Qb, Kb, Vt);
    attn_kernel<<<dim3(64, 8), 512, 0, stream>>>(Qb, Kb, Vt, AO);
    gemm_out_kernel<<<dim3(64, 8), 256, 0, stream>>>(AO, wob, bo, out);
}